// Round 1
// baseline (695.052 us; speedup 1.0000x reference)
//
#include <hip/hip_runtime.h>
#include <cstdint>
#include <cstddef>

// Problem constants (fixed by reference)
#define NH   8
#define LSEQ 2048
#define DH   64
#define BQ   64
#define BK   64
#define NKT  (LSEQ / BK)   // 32 k-tiles

__device__ __forceinline__ float softplusf(float x) {
    // stable: max(x,0) + log1p(exp(-|x|)) — matches jax.nn.softplus
    return fmaxf(x, 0.0f) + log1pf(__expf(-fabsf(x)));
}

// Main fused kernel: one block per (head, 64-row q-tile).
// Writes UNNORMALIZED e = exp(s - 8) into the probs region; computes
// out = (sum_k e * c * v) / (sum_k e) exactly (c folded into V staging).
// probs normalization (× c[k] / l[q]) happens in norm_kernel.
__global__ void attn_main(const float* __restrict__ qp,  const float* __restrict__ kp,
                          const float* __restrict__ vp,  const float* __restrict__ cp,
                          const float* __restrict__ dqp, const float* __restrict__ dktp,
                          const float* __restrict__ dkbp,const float* __restrict__ dksp,
                          const float* __restrict__ rtp, const float* __restrict__ rbp,
                          const float* __restrict__ Wwp, const float* __restrict__ Wbp,
                          float* __restrict__ outp, float* __restrict__ probp)
{
    // LDS: transposed tiles for outer-product micro-kernels (stride 68 = 4-dword aligned, bank-safe)
    __shared__ float qT[64][68];     // [d][qq]
    __shared__ float kT[64][68];     // [d][kk]  -- reused as eT[kk][qq] after QK phase
    __shared__ float vT[64][68];     // [kk][d]  (c[k] folded in)
    __shared__ float meta[64][12];   // per-k folded bias coefficients
    __shared__ float dqs[64][3];
    __shared__ float stats[64][16];
    __shared__ float lrow[64];

    const int bid = blockIdx.x;
    const int h   = bid >> 5;        // 32 q-tiles per head
    const int qt  = bid & 31;
    const int q0  = qt * BQ;
    const int t   = threadIdx.x;
    const int tx  = t & 15,  ty  = t >> 4;
    const int tx4 = tx * 4,  ty4 = ty * 4;

    // W columns for this head: W_w, W_b are [F=4][H=8]
    float Ww[4], Wb[4];
#pragma unroll
    for (int f = 0; f < 4; ++f) { Ww[f] = Wwp[f * NH + h]; Wb[f] = Wbp[f * NH + h]; }

    // ---- stage q-tile (transposed) + d_q rows ----
    {
        const int qq0 = t >> 4, d4 = t & 15;
#pragma unroll
        for (int rr = 0; rr < 4; ++rr) {
            const int qq = qq0 + rr * 16;
            const float4 x = *(const float4*)(qp + ((size_t)(h * LSEQ + q0 + qq)) * DH + d4 * 4);
            qT[d4 * 4 + 0][qq] = x.x; qT[d4 * 4 + 1][qq] = x.y;
            qT[d4 * 4 + 2][qq] = x.z; qT[d4 * 4 + 3][qq] = x.w;
        }
        if (t < 64) {
            dqs[t][0] = dqp[(q0 + t) * 3 + 0];
            dqs[t][1] = dqp[(q0 + t) * 3 + 1];
            dqs[t][2] = dqp[(q0 + t) * 3 + 2];
        }
    }
    __syncthreads();

    float dq0[4], dq1[4], dq2[4];
#pragma unroll
    for (int r = 0; r < 4; ++r) {
        dq0[r] = dqs[ty4 + r][0]; dq1[r] = dqs[ty4 + r][1]; dq2[r] = dqs[ty4 + r][2];
    }

    float acc[4][4] = {};     // PV accumulator (out tile)
    float lpart[4]  = {};     // row-sum partials of e

    for (int kt = 0; kt < NKT; ++kt) {
        const int k0 = kt * BK;
        __syncthreads();  // previous tile's eT/vT fully consumed

        // ---- stage k-tile (transposed), v-tile (×c), per-k meta ----
        {
            const int kk0 = t >> 4, d4 = t & 15;
#pragma unroll
            for (int rr = 0; rr < 4; ++rr) {
                const int kk = kk0 + rr * 16;
                const size_t rowoff = ((size_t)(h * LSEQ + k0 + kk)) * DH + d4 * 4;
                const float4 x = *(const float4*)(kp + rowoff);
                kT[d4 * 4 + 0][kk] = x.x; kT[d4 * 4 + 1][kk] = x.y;
                kT[d4 * 4 + 2][kk] = x.z; kT[d4 * 4 + 3][kk] = x.w;
                float4 y = *(const float4*)(vp + rowoff);
                const float cv = cp[k0 + kk];
                y.x *= cv; y.y *= cv; y.z *= cv; y.w *= cv;
                *(float4*)&vT[kk][d4 * 4] = y;
            }
            if (t < 64) {
                const int kg = k0 + t;
                const float* sc = dksp + (size_t)kg * 8;  // [2][4]: top scores then bottom
                const float* tp = dktp + (size_t)kg * 3;
                const float* bt = dkbp + (size_t)kg * 3;
                float cw = 0.0f, cb = 0.0f;
#pragma unroll
                for (int f = 0; f < 3; ++f) {
                    const float stf = sc[f], sbf = sc[4 + f];
                    const float A  = stf + sbf;
                    const float Bv = tp[f] * stf + bt[f] * sbf;
                    meta[t][f]     = A * Ww[f];
                    meta[t][4 + f] = A * Wb[f];
                    cw -= Bv * Ww[f];
                    cb -= Bv * Wb[f];
                }
                meta[t][3]  = cw;             meta[t][7]  = cb;
                meta[t][8]  = sc[3] * Ww[3];  meta[t][9]  = sc[7] * Ww[3];
                meta[t][10] = sc[3] * Wb[3];  meta[t][11] = sc[7] * Wb[3];
            }
        }
        __syncthreads();

        // ---- QK^T micro (4x4 outer product over d) ----
        float s[4][4] = {};
#pragma unroll 8
        for (int d = 0; d < 64; ++d) {
            const float4 a = *(const float4*)&qT[d][ty4];
            const float4 b = *(const float4*)&kT[d][tx4];
            s[0][0] += a.x * b.x; s[0][1] += a.x * b.y; s[0][2] += a.x * b.z; s[0][3] += a.x * b.w;
            s[1][0] += a.y * b.x; s[1][1] += a.y * b.y; s[1][2] += a.y * b.z; s[1][3] += a.y * b.w;
            s[2][0] += a.z * b.x; s[2][1] += a.z * b.y; s[2][2] += a.z * b.z; s[2][3] += a.z * b.w;
            s[3][0] += a.w * b.x; s[3][1] += a.w * b.y; s[3][2] += a.w * b.z; s[3][3] += a.w * b.w;
        }
        __syncthreads();  // done reading kT; about to overwrite it with eT

        // ---- bias + softplus gate + exp; write e to LDS (transposed) + global probs ----
        {
            float rt_[4][4], rb_[4][4];
#pragma unroll
            for (int r = 0; r < 4; ++r) {
                const int q = q0 + ty4 + r;
                const float4 a = *(const float4*)(rtp + (size_t)q * LSEQ + k0 + tx4);
                const float4 b = *(const float4*)(rbp + (size_t)q * LSEQ + k0 + tx4);
                rt_[r][0] = a.x; rt_[r][1] = a.y; rt_[r][2] = a.z; rt_[r][3] = a.w;
                rb_[r][0] = b.x; rb_[r][1] = b.y; rb_[r][2] = b.z; rb_[r][3] = b.w;
            }
            float pg[4][4];
#pragma unroll
            for (int c = 0; c < 4; ++c) {
                const int kc = tx4 + c;
                const float m0 = meta[kc][0],  m1 = meta[kc][1],  m2  = meta[kc][2],  m3  = meta[kc][3];
                const float m4 = meta[kc][4],  m5 = meta[kc][5],  m6  = meta[kc][6],  m7  = meta[kc][7];
                const float m8 = meta[kc][8],  m9 = meta[kc][9],  m10 = meta[kc][10], m11 = meta[kc][11];
                float ecv[4];
#pragma unroll
                for (int r = 0; r < 4; ++r) {
                    const float rt = rt_[r][c], rb = rb_[r][c];
                    float ww = m3 + dq0[r] * m0 + dq1[r] * m1 + dq2[r] * m2 + rt * m8  + rb * m9;
                    float bb = m7 + dq0[r] * m4 + dq1[r] * m5 + dq2[r] * m6 + rt * m10 + rb * m11;
                    const float w  = softplusf(ww);
                    const float sv = s[r][c] * 0.125f * w + bb;
                    const float e  = __expf(sv - 8.0f);   // constant shift; cancels in normalization
                    lpart[r] += e;
                    pg[r][c] = e;
                    ecv[r]   = e;
                }
                *(float4*)&kT[kc][ty4] = make_float4(ecv[0], ecv[1], ecv[2], ecv[3]);  // eT[kk][qq]
            }
#pragma unroll
            for (int r = 0; r < 4; ++r) {
                const int q = q0 + ty4 + r;
                *(float4*)(probp + ((size_t)(h * LSEQ + q)) * LSEQ + k0 + tx4) =
                    make_float4(pg[r][0], pg[r][1], pg[r][2], pg[r][3]);
            }
        }
        __syncthreads();  // eT visible

        // ---- PV micro (4x4 outer product over kk) ----
#pragma unroll 8
        for (int kk = 0; kk < 64; ++kk) {
            const float4 e4 = *(const float4*)&kT[kk][ty4];   // eT
            const float4 v4 = *(const float4*)&vT[kk][tx4];
            acc[0][0] += e4.x * v4.x; acc[0][1] += e4.x * v4.y; acc[0][2] += e4.x * v4.z; acc[0][3] += e4.x * v4.w;
            acc[1][0] += e4.y * v4.x; acc[1][1] += e4.y * v4.y; acc[1][2] += e4.y * v4.z; acc[1][3] += e4.y * v4.w;
            acc[2][0] += e4.z * v4.x; acc[2][1] += e4.z * v4.y; acc[2][2] += e4.z * v4.z; acc[2][3] += e4.z * v4.w;
            acc[3][0] += e4.w * v4.x; acc[3][1] += e4.w * v4.y; acc[3][2] += e4.w * v4.z; acc[3][3] += e4.w * v4.w;
        }
    }

    // ---- reduce row sums, scale + write out ----
    __syncthreads();
#pragma unroll
    for (int r = 0; r < 4; ++r) stats[ty4 + r][tx] = lpart[r];
    __syncthreads();
    if (t < 64) {
        float l = 0.0f;
#pragma unroll
        for (int j = 0; j < 16; ++j) l += stats[t][j];
        lrow[t] = 1.0f / l;
    }
    __syncthreads();
#pragma unroll
    for (int r = 0; r < 4; ++r) {
        const float li = lrow[ty4 + r];
        const int q = q0 + ty4 + r;
        *(float4*)(outp + ((size_t)(h * LSEQ + q)) * DH + tx4) =
            make_float4(acc[r][0] * li, acc[r][1] * li, acc[r][2] * li, acc[r][3] * li);
    }
}

// Normalize probs in place: p[row][k] = e[row][k] * c[k] / sum_k e[row][k].
// One block per row; the needed sum is exactly the stored data -> no workspace.
__global__ void norm_kernel(float* __restrict__ probp, const float* __restrict__ cp)
{
    const int row = blockIdx.x;                    // 0 .. NH*LSEQ-1
    float* p = probp + (size_t)row * LSEQ;
    const int t = threadIdx.x;

    float4 x0 = *(const float4*)(p + t * 4);
    float4 x1 = *(const float4*)(p + (t + 256) * 4);
    float sum = x0.x + x0.y + x0.z + x0.w + x1.x + x1.y + x1.z + x1.w;

#pragma unroll
    for (int o = 32; o > 0; o >>= 1) sum += __shfl_xor(sum, o, 64);

    __shared__ float wsum[4];
    const int wave = t >> 6, lane = t & 63;
    if (lane == 0) wsum[wave] = sum;
    __syncthreads();
    const float li = 1.0f / (wsum[0] + wsum[1] + wsum[2] + wsum[3]);

    const float4 c0 = *(const float4*)(cp + t * 4);
    const float4 c1 = *(const float4*)(cp + (t + 256) * 4);
    x0.x *= li * c0.x; x0.y *= li * c0.y; x0.z *= li * c0.z; x0.w *= li * c0.w;
    x1.x *= li * c1.x; x1.y *= li * c1.y; x1.z *= li * c1.z; x1.w *= li * c1.w;
    *(float4*)(p + t * 4)         = x0;
    *(float4*)(p + (t + 256) * 4) = x1;
}

extern "C" void kernel_launch(void* const* d_in, const int* in_sizes, int n_in,
                              void* d_out, int out_size, void* d_ws, size_t ws_size,
                              hipStream_t stream)
{
    (void)in_sizes; (void)n_in; (void)d_ws; (void)ws_size; (void)out_size;
    const float* qp   = (const float*)d_in[0];
    const float* kp   = (const float*)d_in[1];
    const float* vp   = (const float*)d_in[2];
    const float* cp   = (const float*)d_in[3];
    const float* dqp  = (const float*)d_in[4];
    const float* dktp = (const float*)d_in[5];
    const float* dkbp = (const float*)d_in[6];
    const float* dksp = (const float*)d_in[7];
    const float* rtp  = (const float*)d_in[8];
    const float* rbp  = (const float*)d_in[9];
    const float* Wwp  = (const float*)d_in[10];
    const float* Wbp  = (const float*)d_in[11];

    float* outp  = (float*)d_out;                       // [1,8,2048,64]
    float* probp = (float*)d_out + (size_t)NH * LSEQ * DH;  // [1,8,2048,2048]

    attn_main<<<dim3(NH * (LSEQ / BQ)), dim3(256), 0, stream>>>(
        qp, kp, vp, cp, dqp, dktp, dkbp, dksp, rtp, rbp, Wwp, Wbp, outp, probp);

    norm_kernel<<<dim3(NH * LSEQ), dim3(256), 0, stream>>>(probp, cp);
}

// Round 3
// 292.945 us; speedup vs baseline: 2.3726x; 2.3726x over previous
//
#include <hip/hip_runtime.h>
#include <cstdint>
#include <cstddef>

#define NH 8
#define LQ 2048
#define DH 64
#define NKT_HALF 16   // split-k: each block does 16 of the 32 k-tiles

typedef __attribute__((ext_vector_type(8))) __bf16 bf16x8;
typedef __attribute__((ext_vector_type(8))) unsigned short ushort8;
typedef __attribute__((ext_vector_type(4))) float floatx4;

__device__ __forceinline__ unsigned short bf_trunc(float x) {
    return (unsigned short)(__float_as_uint(x) >> 16);
}
__device__ __forceinline__ float bf_up(unsigned short h) {
    return __uint_as_float(((unsigned int)h) << 16);
}
__device__ __forceinline__ unsigned short bf_rne(float x) {
    unsigned int u = __float_as_uint(x);
    return (unsigned short)((u + 0x7FFFu + ((u >> 16) & 1u)) >> 16);
}
struct hl_t { unsigned short h, l; };
// x ~= h + l with |x-h-l| <= 2^-16 |x|
__device__ __forceinline__ hl_t split2(float x) {
    hl_t r;
    r.h = bf_trunc(x);
    r.l = bf_trunc(x - bf_up(r.h));
    return r;
}

#define MFMA16(A, B, C) __builtin_amdgcn_mfma_f32_16x16x32_bf16((A), (B), (C), 0, 0, 0)

// Grid: 512 = 32 qt * 8 h * 2 half. Block: 256 thr (4 waves, 16 q-rows each).
// Writes unnormalized e=exp(s-8) to probs, PV/l partials to ws.
__global__ __launch_bounds__(256, 3) void attn_main(
    const float* __restrict__ qp,  const float* __restrict__ kp,
    const float* __restrict__ vp,  const float* __restrict__ cp,
    const float* __restrict__ dqp, const float* __restrict__ dktp,
    const float* __restrict__ dkbp,const float* __restrict__ dksp,
    const float* __restrict__ rtp, const float* __restrict__ rbp,
    const float* __restrict__ Wwp, const float* __restrict__ Wbp,
    float* __restrict__ probp, float* __restrict__ lws, float* __restrict__ pvws)
{
    // 40960 B total -> 4 blocks/CU by LDS
    __shared__ unsigned short sh_khi[64 * 72];   // Q-hi staging, then K-hi
    __shared__ unsigned short sh_klo[64 * 72];   // Q-lo staging, then K-lo, then ebf (P tile bf16)
    __shared__ unsigned short sh_vhi[64 * 72];   // V^T hi (c folded in)
    __shared__ unsigned short sh_vlo[64 * 72];   // V^T lo
    __shared__ float sh_meta[64 * 13];
    __shared__ float sh_dqs[64 * 3];

    const int bid  = blockIdx.x;
    const int half = bid & 1;
    const int h    = (bid >> 1) & 7;
    const int qt   = bid >> 4;
    const int q0   = qt * 64;
    const int t    = threadIdx.x;
    const int lane = t & 63;
    const int m    = lane & 15;
    const int quad = lane >> 4;
    const int w16  = (t >> 6) * 16;

    float Ww[4], Wb[4];
#pragma unroll
    for (int f = 0; f < 4; ++f) { Ww[f] = Wwp[f * NH + h]; Wb[f] = Wbp[f * NH + h]; }

    // ---- stage Q (hi/lo) into the K buffers, load dqs ----
    {
        const int row = t >> 2, s = t & 3;
        const float* src = qp + ((size_t)(h * LQ + q0 + row)) * DH + s * 16;
        ushort8 vh0, vh1, vl0, vl1;
#pragma unroll
        for (int j = 0; j < 2; ++j) {
            float4 x = *(const float4*)(src + 4 * j);
            hl_t a = split2(x.x), b = split2(x.y), c = split2(x.z), d = split2(x.w);
            vh0[4 * j + 0] = a.h; vl0[4 * j + 0] = a.l;
            vh0[4 * j + 1] = b.h; vl0[4 * j + 1] = b.l;
            vh0[4 * j + 2] = c.h; vl0[4 * j + 2] = c.l;
            vh0[4 * j + 3] = d.h; vl0[4 * j + 3] = d.l;
        }
#pragma unroll
        for (int j = 0; j < 2; ++j) {
            float4 x = *(const float4*)(src + 8 + 4 * j);
            hl_t a = split2(x.x), b = split2(x.y), c = split2(x.z), d = split2(x.w);
            vh1[4 * j + 0] = a.h; vl1[4 * j + 0] = a.l;
            vh1[4 * j + 1] = b.h; vl1[4 * j + 1] = b.l;
            vh1[4 * j + 2] = c.h; vl1[4 * j + 2] = c.l;
            vh1[4 * j + 3] = d.h; vl1[4 * j + 3] = d.l;
        }
        const int base = row * 72 + s * 16;
        *(ushort8*)&sh_khi[base] = vh0;  *(ushort8*)&sh_khi[base + 8] = vh1;
        *(ushort8*)&sh_klo[base] = vl0;  *(ushort8*)&sh_klo[base + 8] = vl1;
        if (t < 64) {
            sh_dqs[t * 3 + 0] = dqp[(q0 + t) * 3 + 0];
            sh_dqs[t * 3 + 1] = dqp[(q0 + t) * 3 + 1];
            sh_dqs[t * 3 + 2] = dqp[(q0 + t) * 3 + 2];
        }
    }
    __syncthreads();

    // Q A-fragments live in registers for the whole kernel
    bf16x8 aqh[2], aql[2];
#pragma unroll
    for (int kc = 0; kc < 2; ++kc) {
        aqh[kc] = *(const bf16x8*)&sh_khi[(w16 + m) * 72 + kc * 32 + quad * 8];
        aql[kc] = *(const bf16x8*)&sh_klo[(w16 + m) * 72 + kc * 32 + quad * 8];
    }
    float dq0[4], dq1[4], dq2[4];
#pragma unroll
    for (int r = 0; r < 4; ++r) {
        const int row = w16 + quad * 4 + r;
        dq0[r] = sh_dqs[row * 3 + 0]; dq1[r] = sh_dqs[row * 3 + 1]; dq2[r] = sh_dqs[row * 3 + 2];
    }
    __syncthreads();   // Q buffers free for K staging

    const floatx4 zf = {0.f, 0.f, 0.f, 0.f};
    floatx4 pacc[4] = {zf, zf, zf, zf};
    float lpart[4] = {0.f, 0.f, 0.f, 0.f};

    for (int kth = 0; kth < NKT_HALF; ++kth) {
        const int k0 = (half * NKT_HALF + kth) * 64;

        // ---- stage K (hi/lo, row-major) ----
        {
            const int row = t >> 2, s = t & 3;
            const float* src = kp + ((size_t)(h * LQ + k0 + row)) * DH + s * 16;
            ushort8 vh0, vh1, vl0, vl1;
#pragma unroll
            for (int j = 0; j < 2; ++j) {
                float4 x = *(const float4*)(src + 4 * j);
                hl_t a = split2(x.x), b = split2(x.y), c = split2(x.z), d = split2(x.w);
                vh0[4 * j + 0] = a.h; vl0[4 * j + 0] = a.l;
                vh0[4 * j + 1] = b.h; vl0[4 * j + 1] = b.l;
                vh0[4 * j + 2] = c.h; vl0[4 * j + 2] = c.l;
                vh0[4 * j + 3] = d.h; vl0[4 * j + 3] = d.l;
            }
#pragma unroll
            for (int j = 0; j < 2; ++j) {
                float4 x = *(const float4*)(src + 8 + 4 * j);
                hl_t a = split2(x.x), b = split2(x.y), c = split2(x.z), d = split2(x.w);
                vh1[4 * j + 0] = a.h; vl1[4 * j + 0] = a.l;
                vh1[4 * j + 1] = b.h; vl1[4 * j + 1] = b.l;
                vh1[4 * j + 2] = c.h; vl1[4 * j + 2] = c.l;
                vh1[4 * j + 3] = d.h; vl1[4 * j + 3] = d.l;
            }
            const int base = row * 72 + s * 16;
            *(ushort8*)&sh_khi[base] = vh0;  *(ushort8*)&sh_khi[base + 8] = vh1;
            *(ushort8*)&sh_klo[base] = vl0;  *(ushort8*)&sh_klo[base + 8] = vl1;
        }
        // ---- stage V transposed (hi/lo), c folded in; packed b32 writes (conflict-free) ----
        {
            const int p = t >> 4;    // 0..15 -> kk pair
            const int mm = t & 15;
#pragma unroll
            for (int g = 0; g < 2; ++g) {
                const int kka = 2 * p + 32 * g;
                const float ca = cp[k0 + kka], cb = cp[k0 + kka + 1];
                const float* va = vp + ((size_t)(h * LQ + k0 + kka)) * DH;
                const float* vb = va + DH;
#pragma unroll
                for (int dd = 0; dd < 4; ++dd) {
                    const int d = mm + 16 * dd;
                    hl_t xa = split2(va[d] * ca);
                    hl_t xb = split2(vb[d] * cb);
                    *(unsigned int*)&sh_vhi[d * 72 + kka] = (unsigned int)xa.h | ((unsigned int)xb.h << 16);
                    *(unsigned int*)&sh_vlo[d * 72 + kka] = (unsigned int)xa.l | ((unsigned int)xb.l << 16);
                }
            }
        }
        // ---- per-k folded bias coefficients ----
        if (t < 64) {
            const int kg = k0 + t;
            const float* sc_ = dksp + (size_t)kg * 8;   // [2][4] top then bottom
            const float* tp  = dktp + (size_t)kg * 3;
            const float* bt  = dkbp + (size_t)kg * 3;
            float cw = 0.f, cb2 = 0.f;
#pragma unroll
            for (int f = 0; f < 3; ++f) {
                const float stf = sc_[f], sbf = sc_[4 + f];
                const float A  = stf + sbf;
                const float Bv = tp[f] * stf + bt[f] * sbf;
                sh_meta[t * 13 + f]     = A * Ww[f];
                sh_meta[t * 13 + 4 + f] = A * Wb[f];
                cw  -= Bv * Ww[f];
                cb2 -= Bv * Wb[f];
            }
            sh_meta[t * 13 + 3]  = cw;              sh_meta[t * 13 + 7]  = cb2;
            sh_meta[t * 13 + 8]  = sc_[3] * Ww[3];  sh_meta[t * 13 + 9]  = sc_[7] * Ww[3];
            sh_meta[t * 13 + 10] = sc_[3] * Wb[3];  sh_meta[t * 13 + 11] = sc_[7] * Wb[3];
        }
        __syncthreads();

        // ---- prefetch rel features (hidden behind MFMA phase) ----
        float rt_[4][4], rb_[4][4];
#pragma unroll
        for (int r = 0; r < 4; ++r) {
            const size_t q = (size_t)(q0 + w16 + quad * 4 + r);
#pragma unroll
            for (int nt = 0; nt < 4; ++nt) {
                rt_[nt][r] = rtp[q * LQ + k0 + nt * 16 + m];
                rb_[nt][r] = rbp[q * LQ + k0 + nt * 16 + m];
            }
        }

        // ---- QK^T: 3-term split-bf16 MFMA ----
        floatx4 sc[4] = {zf, zf, zf, zf};
#pragma unroll
        for (int nt = 0; nt < 4; ++nt) {
#pragma unroll
            for (int kc = 0; kc < 2; ++kc) {
                const int kb = (nt * 16 + m) * 72 + kc * 32 + quad * 8;
                bf16x8 bh = *(const bf16x8*)&sh_khi[kb];
                bf16x8 bl = *(const bf16x8*)&sh_klo[kb];
                sc[nt] = MFMA16(aqh[kc], bh, sc[nt]);
                sc[nt] = MFMA16(aql[kc], bh, sc[nt]);
                sc[nt] = MFMA16(aqh[kc], bl, sc[nt]);
            }
        }
        __syncthreads();   // all waves done with K-lo -> reuse as ebf

        // ---- epilogue: gate + bias + exp; probs store; P->LDS (bf16, A-layout rows) ----
        unsigned short* ebf = sh_klo;
#pragma unroll
        for (int nt = 0; nt < 4; ++nt) {
            const int kcol = nt * 16 + m;
            const float m0 = sh_meta[kcol * 13 + 0],  m1 = sh_meta[kcol * 13 + 1];
            const float m2 = sh_meta[kcol * 13 + 2],  m3 = sh_meta[kcol * 13 + 3];
            const float m4 = sh_meta[kcol * 13 + 4],  m5 = sh_meta[kcol * 13 + 5];
            const float m6 = sh_meta[kcol * 13 + 6],  m7 = sh_meta[kcol * 13 + 7];
            const float m8 = sh_meta[kcol * 13 + 8],  m9 = sh_meta[kcol * 13 + 9];
            const float mA = sh_meta[kcol * 13 + 10], mB = sh_meta[kcol * 13 + 11];
#pragma unroll
            for (int r = 0; r < 4; ++r) {
                float ww = fmaf(dq0[r], m0, m3); ww = fmaf(dq1[r], m1, ww); ww = fmaf(dq2[r], m2, ww);
                ww = fmaf(rt_[nt][r], m8, ww);   ww = fmaf(rb_[nt][r], m9, ww);
                float bb = fmaf(dq0[r], m4, m7); bb = fmaf(dq1[r], m5, bb); bb = fmaf(dq2[r], m6, bb);
                bb = fmaf(rt_[nt][r], mA, bb);   bb = fmaf(rb_[nt][r], mB, bb);
                const float wg = fmaxf(ww, 0.f) + __logf(1.f + __expf(-fabsf(ww)));
                const float sv = fmaf(sc[nt][r] * 0.125f, wg, bb);
                const float e  = __expf(sv - 8.0f);   // constant shift cancels in normalization
                lpart[r] += e;
                probp[((size_t)(h * LQ + q0 + w16 + quad * 4 + r)) * LQ + k0 + kcol] = e;
                ebf[(w16 + quad * 4 + r) * 72 + kcol] = bf_rne(e);
            }
        }

        // ---- PV: bf16 P x split-bf16 V (own-wave rows; no barrier needed before reads) ----
        bf16x8 ap0 = *(const bf16x8*)&ebf[(w16 + m) * 72 + quad * 8];
        bf16x8 ap1 = *(const bf16x8*)&ebf[(w16 + m) * 72 + 32 + quad * 8];
#pragma unroll
        for (int nt = 0; nt < 4; ++nt) {
            const int vb = (nt * 16 + m) * 72 + quad * 8;
            bf16x8 bh0 = *(const bf16x8*)&sh_vhi[vb];
            bf16x8 bl0 = *(const bf16x8*)&sh_vlo[vb];
            bf16x8 bh1 = *(const bf16x8*)&sh_vhi[vb + 32];
            bf16x8 bl1 = *(const bf16x8*)&sh_vlo[vb + 32];
            pacc[nt] = MFMA16(ap0, bh0, pacc[nt]);
            pacc[nt] = MFMA16(ap0, bl0, pacc[nt]);
            pacc[nt] = MFMA16(ap1, bh1, pacc[nt]);
            pacc[nt] = MFMA16(ap1, bl1, pacc[nt]);
        }
        __syncthreads();   // ebf/vT consumed before next staging
    }

    // ---- row-sum partials: reduce over the 16 m-lanes (quad-local via shfl_xor) ----
#pragma unroll
    for (int off = 1; off < 16; off <<= 1) {
#pragma unroll
        for (int r = 0; r < 4; ++r) lpart[r] += __shfl_xor(lpart[r], off, 64);
    }
    if (m == 0) {
#pragma unroll
        for (int r = 0; r < 4; ++r)
            lws[half * (NH * LQ) + h * LQ + q0 + w16 + quad * 4 + r] = lpart[r];
    }
    // ---- PV partials to ws ----
#pragma unroll
    for (int nt = 0; nt < 4; ++nt) {
#pragma unroll
        for (int r = 0; r < 4; ++r) {
            const size_t row = (size_t)(h * LQ + q0 + w16 + quad * 4 + r);
            pvws[(size_t)half * (NH * LQ * DH) + row * DH + nt * 16 + m] = pacc[nt][r];
        }
    }
}

// out = (pv0 + pv1) / (l0 + l1)
__global__ void combine_kernel(const float* __restrict__ pvws, const float* __restrict__ lws,
                               float* __restrict__ outp)
{
    const int idx4 = blockIdx.x * 256 + threadIdx.x;   // 0..262143
    const int row  = idx4 >> 4;
    const int d4   = (idx4 & 15) * 4;
    const float4 a = *(const float4*)(pvws + (size_t)row * DH + d4);
    const float4 b = *(const float4*)(pvws + (size_t)(NH * LQ * DH) + (size_t)row * DH + d4);
    const float rl = 1.0f / (lws[row] + lws[NH * LQ + row]);
    *(float4*)(outp + (size_t)row * DH + d4) =
        make_float4((a.x + b.x) * rl, (a.y + b.y) * rl, (a.z + b.z) * rl, (a.w + b.w) * rl);
}

// probs[row][k] = e[row][k] * c[k] / l[row]   (pure elementwise; l from ws)
__global__ void norm_kernel(float* __restrict__ probp, const float* __restrict__ cp,
                            const float* __restrict__ lws)
{
    const int row = blockIdx.x;
    const float rl = 1.0f / (lws[row] + lws[NH * LQ + row]);
    float* p = probp + (size_t)row * LQ;
    const int t = threadIdx.x;
    float4 x0 = *(const float4*)(p + t * 4);
    float4 x1 = *(const float4*)(p + (t + 256) * 4);
    const float4 c0 = *(const float4*)(cp + t * 4);
    const float4 c1 = *(const float4*)(cp + (t + 256) * 4);
    x0.x *= rl * c0.x; x0.y *= rl * c0.y; x0.z *= rl * c0.z; x0.w *= rl * c0.w;
    x1.x *= rl * c1.x; x1.y *= rl * c1.y; x1.z *= rl * c1.z; x1.w *= rl * c1.w;
    *(float4*)(p + t * 4)         = x0;
    *(float4*)(p + (t + 256) * 4) = x1;
}

extern "C" void kernel_launch(void* const* d_in, const int* in_sizes, int n_in,
                              void* d_out, int out_size, void* d_ws, size_t ws_size,
                              hipStream_t stream)
{
    (void)in_sizes; (void)n_in; (void)ws_size; (void)out_size;
    const float* qp   = (const float*)d_in[0];
    const float* kp   = (const float*)d_in[1];
    const float* vp   = (const float*)d_in[2];
    const float* cp   = (const float*)d_in[3];
    const float* dqp  = (const float*)d_in[4];
    const float* dktp = (const float*)d_in[5];
    const float* dkbp = (const float*)d_in[6];
    const float* dksp = (const float*)d_in[7];
    const float* rtp  = (const float*)d_in[8];
    const float* rbp  = (const float*)d_in[9];
    const float* Wwp  = (const float*)d_in[10];
    const float* Wbp  = (const float*)d_in[11];

    float* outp  = (float*)d_out;                            // [1,8,2048,64]
    float* probp = (float*)d_out + (size_t)NH * LQ * DH;     // [1,8,2048,2048]

    float* lws  = (float*)d_ws;                              // [2][16384]
    float* pvws = (float*)d_ws + 2 * (NH * LQ);              // [2][16384*64]  (~8.5 MB total)

    attn_main<<<dim3(512), dim3(256), 0, stream>>>(
        qp, kp, vp, cp, dqp, dktp, dkbp, dksp, rtp, rbp, Wwp, Wbp, probp, lws, pvws);
    combine_kernel<<<dim3(1024), dim3(256), 0, stream>>>(pvws, lws, outp);
    norm_kernel<<<dim3(NH * LQ), dim3(256), 0, stream>>>(probp, cp, lws);
}